// Round 1
// baseline (99.859 us; speedup 1.0000x reference)
//
#include <hip/hip_runtime.h>
#include <math.h>

#define BB 16
#define NN 128
#define TT 512
#define CC 64
#define HH 64

__device__ __forceinline__ float wsum64(float v) {
#pragma unroll
  for (int m = 1; m < 64; m <<= 1) v += __shfl_xor(v, m, 64);
  return v;
}

// Kernel A: fused mean-over-N + Q/K projection + LayerNorm + L2 normalize.
// grid = BB*32 = 512 blocks, 256 threads. Each block: 16 rows (t) of one batch.
// Writes Kmat (B,T,H) row-major and Qt (B,H,T) transposed (for scalar loads in kernel B).
__global__ __launch_bounds__(256) void fused_mean_proj(
    const float* __restrict__ x, const float* __restrict__ Wq,
    const float* __restrict__ bq, const float* __restrict__ Wk,
    const float* __restrict__ bk, float* __restrict__ Qt,
    float* __restrict__ Kmat) {
  __shared__ float Wq_s[64 * 65];   // [c][h], pad 65 -> conflict-free lane-h reads
  __shared__ float Wk_s[64 * 65];
  __shared__ float xm_s[16 * 64];   // x_mean tile [row][c]
  __shared__ float qt_s[64 * 17];   // [h][row], pad 17 -> conflict-free writes

  const int tid = threadIdx.x;
  const int b = blockIdx.x >> 5;
  const int t0 = (blockIdx.x & 31) << 4;

  // Stage W transposed into LDS (one-time; coalesced global reads).
#pragma unroll
  for (int it = 0; it < 16; ++it) {
    int i = it * 256 + tid;
    int h = i >> 6, c = i & 63;
    Wq_s[c * 65 + h] = Wq[i];
    Wk_s[c * 65 + h] = Wk[i];
  }

  // Mean over N: thread (j = row-in-tile, c4 = float4 column). Fully coalesced.
  {
    const int j = tid >> 4;
    const int c4 = tid & 15;
    const float4* xp = (const float4*)x;
    size_t base4 = ((size_t)b * NN * TT + (size_t)(t0 + j)) * 16 + c4;
    float4 s = {0.f, 0.f, 0.f, 0.f};
#pragma unroll 8
    for (int n = 0; n < NN; ++n) {
      float4 v = xp[base4 + (size_t)n * (TT * 16)];
      s.x += v.x; s.y += v.y; s.z += v.z; s.w += v.w;
    }
    const float inv = 1.0f / (float)NN;
    float4 xm4;
    xm4.x = s.x * inv; xm4.y = s.y * inv; xm4.z = s.z * inv; xm4.w = s.w * inv;
    *(float4*)&xm_s[j * 64 + c4 * 4] = xm4;
  }
  __syncthreads();

  // Projection: wave rw handles rows rw*4 .. rw*4+3; lane = output channel h.
  const int rw = tid >> 6;
  const int h = tid & 63;
  float qa[4], ka[4];
  const float bqv = bq[h], bkv = bk[h];
#pragma unroll
  for (int r = 0; r < 4; ++r) { qa[r] = bqv; ka[r] = bkv; }
#pragma unroll
  for (int c = 0; c < 64; ++c) {
    float wq = Wq_s[c * 65 + h];   // stride-65: conflict-free
    float wk = Wk_s[c * 65 + h];
#pragma unroll
    for (int r = 0; r < 4; ++r) {
      float xv = xm_s[(rw * 4 + r) * 64 + c];  // wave-uniform addr: broadcast
      qa[r] = fmaf(xv, wq, qa[r]);
      ka[r] = fmaf(xv, wk, ka[r]);
    }
  }

  // LayerNorm + L2 per row (reductions across the 64 lanes of this wave).
#pragma unroll
  for (int r = 0; r < 4; ++r) {
    const int t = t0 + rw * 4 + r;
    // Q path
    float mq = wsum64(qa[r]) * (1.f / 64.f);
    float dq = qa[r] - mq;
    float vq = wsum64(dq * dq) * (1.f / 64.f);
    float yq = dq / sqrtf(vq + 1e-5f);
    float nq = sqrtf(wsum64(yq * yq));
    yq = yq / fmaxf(nq, 1e-12f);
    qt_s[h * 17 + rw * 4 + r] = yq;
    // K path
    float mk = wsum64(ka[r]) * (1.f / 64.f);
    float dk = ka[r] - mk;
    float vk = wsum64(dk * dk) * (1.f / 64.f);
    float yk = dk / sqrtf(vk + 1e-5f);
    float nk = sqrtf(wsum64(yk * yk));
    yk = yk / fmaxf(nk, 1e-12f);
    Kmat[((size_t)b * TT + t) * HH + h] = yk;   // coalesced
  }
  __syncthreads();

  // Write Qt (B,H,T): thread -> (h, 4-float chunk of the 16 t's).
  {
    const int hh = tid >> 2, part = tid & 3;
    float4 o;
    o.x = qt_s[hh * 17 + part * 4 + 0];
    o.y = qt_s[hh * 17 + part * 4 + 1];
    o.z = qt_s[hh * 17 + part * 4 + 2];
    o.w = qt_s[hh * 17 + part * 4 + 3];
    *(float4*)&Qt[((size_t)b * HH + hh) * TT + t0 + part * 4] = o;
  }
}

// Kernel B: logits = clip(Q K^T, -6, 6). grid = 1024 blocks, 256 threads.
// Block-uniform (b, rowgroup of 16); each wave owns 64 columns (lane = col).
// K fragment lives in 64 VGPRs; Q comes from block-uniform Qt rows -> s_load +
// v_fmac with scalar operand. VALU-bound.
__global__ __launch_bounds__(256) void logits_kernel(
    const float* __restrict__ Qt, const float* __restrict__ Kmat,
    float* __restrict__ logits) {
  const int lane = threadIdx.x & 63;
  const int w = threadIdx.x >> 6;
  const int b = blockIdx.x >> 6;           // 0..15
  const int rem = blockIdx.x & 63;
  const int rg = rem >> 1;                 // 0..31 (16-row group)
  const int half = rem & 1;                // which half of the 8 colgroups
  const int r0 = rg * 16;
  const int cg = half * 4 + w;             // 0..7
  const int scol = cg * 64 + lane;

  const float4* kp = (const float4*)(Kmat + ((size_t)b * TT + scol) * HH);
  float4 kv[16];
#pragma unroll
  for (int i = 0; i < 16; ++i) kv[i] = kp[i];

  float acc[16];
#pragma unroll
  for (int r = 0; r < 16; ++r) acc[r] = 0.f;

  const float* qtb = Qt + (size_t)b * HH * TT + r0;  // block-uniform
#pragma unroll
  for (int c4 = 0; c4 < 16; ++c4) {
    float4 k4 = kv[c4];
    const float* q0 = qtb + (size_t)(4 * c4 + 0) * TT;
    const float* q1 = qtb + (size_t)(4 * c4 + 1) * TT;
    const float* q2 = qtb + (size_t)(4 * c4 + 2) * TT;
    const float* q3 = qtb + (size_t)(4 * c4 + 3) * TT;
#pragma unroll
    for (int r = 0; r < 16; ++r) {
      acc[r] = fmaf(q0[r], k4.x, acc[r]);
      acc[r] = fmaf(q1[r], k4.y, acc[r]);
      acc[r] = fmaf(q2[r], k4.z, acc[r]);
      acc[r] = fmaf(q3[r], k4.w, acc[r]);
    }
  }

  float* lrow = logits + ((size_t)b * TT + r0) * TT + cg * 64 + lane;
#pragma unroll
  for (int r = 0; r < 16; ++r) {
    float v = fminf(fmaxf(acc[r], -6.f), 6.f);
    lrow[(size_t)r * TT] = v;
  }
}

// Kernel C: A from band logits. grid = B*T/4 = 2048 blocks, wave per row.
// Replicates: mask -> -1e9, softmax (off-band exp underflows to 0),
// max(.,1e-12), 0.95*A + 0.05/T, min(.,0.35), two normalizations.
__global__ __launch_bounds__(256) void adj_kernel(
    const float* __restrict__ logits, const int* __restrict__ bandp,
    float* __restrict__ A) {
  const int w = threadIdx.x >> 6, lane = threadIdx.x & 63;
  const int row = blockIdx.x * 4 + w;   // row = b*T + t
  const int t = row & (TT - 1);
  const int band = *bandp;
  const float* lrow = logits + (size_t)row * TT;

  float mx = -3.0e38f;
  for (int jj = -band; jj <= band; ++jj) {
    if (jj == 0) continue;
    int ss = t + jj;
    if (ss < 0 || ss >= TT) continue;
    mx = fmaxf(mx, lrow[ss]);
  }
  float den = 0.f;
  int nb = 0;
  for (int jj = -band; jj <= band; ++jj) {
    if (jj == 0) continue;
    int ss = t + jj;
    if (ss < 0 || ss >= TT) continue;
    den += expf(lrow[ss] - mx);
    ++nb;
  }
  const float fl = 0.05f / (float)TT;
  const float offa = 0.95f * 1e-12f + fl;  // off-band value after floor mix
  float bsum = 0.f;
  for (int jj = -band; jj <= band; ++jj) {
    if (jj == 0) continue;
    int ss = t + jj;
    if (ss < 0 || ss >= TT) continue;
    float p = expf(lrow[ss] - mx) / den;
    float a = fminf(0.95f * p + fl, 0.35f);
    bsum += a;
  }
  const float s1 = fmaxf(bsum + (float)(TT - nb) * offa, 1e-12f);
  const float off1 = offa / s1;
  float bsum1 = 0.f;
  for (int jj = -band; jj <= band; ++jj) {
    if (jj == 0) continue;
    int ss = t + jj;
    if (ss < 0 || ss >= TT) continue;
    float p = expf(lrow[ss] - mx) / den;
    float a = fminf(0.95f * p + fl, 0.35f);
    bsum1 += a / s1;
  }
  const float s2 = fmaxf(bsum1 + (float)(TT - nb) * off1, 1e-12f);
  const float off2 = off1 / s2;

  auto colval = [&](int ss) -> float {
    int d = ss - t;
    if (d != 0 && d >= -band && d <= band) {
      float p = expf(lrow[ss] - mx) / den;
      float a = fminf(0.95f * p + fl, 0.35f);
      return a / s1 / s2;
    }
    return off2;
  };

  float* arow = A + (size_t)row * TT + lane * 8;
  const int cb = lane * 8;
  float4 o0, o1;
  o0.x = colval(cb + 0); o0.y = colval(cb + 1);
  o0.z = colval(cb + 2); o0.w = colval(cb + 3);
  o1.x = colval(cb + 4); o1.y = colval(cb + 5);
  o1.z = colval(cb + 6); o1.w = colval(cb + 7);
  *(float4*)&arow[0] = o0;
  *(float4*)&arow[4] = o1;
}

extern "C" void kernel_launch(void* const* d_in, const int* in_sizes, int n_in,
                              void* d_out, int out_size, void* d_ws, size_t ws_size,
                              hipStream_t stream) {
  (void)in_sizes; (void)n_in; (void)out_size; (void)ws_size;
  const float* x  = (const float*)d_in[0];
  const float* Wq = (const float*)d_in[1];
  const float* bq = (const float*)d_in[2];
  const float* Wk = (const float*)d_in[3];
  const float* bk = (const float*)d_in[4];
  const int* band = (const int*)d_in[5];

  float* A = (float*)d_out;                              // (B,T,T)
  float* logits = A + (size_t)BB * TT * TT;              // (B,T,T)
  float* Qt = (float*)d_ws;                              // (B,H,T)
  float* Kmat = Qt + (size_t)BB * HH * TT;               // (B,T,H)

  fused_mean_proj<<<512, 256, 0, stream>>>(x, Wq, bq, Wk, bk, Qt, Kmat);
  logits_kernel<<<1024, 256, 0, stream>>>(Qt, Kmat, logits);
  adj_kernel<<<2048, 256, 0, stream>>>(logits, band, A);
}